// Round 6
// baseline (478.013 us; speedup 1.0000x reference)
//
#include <hip/hip_runtime.h>
#include <stdint.h>

#define D_FEAT 2000
#define D_PAD  2048
#define N_OUT  256
#define ALPHA  0.1f

typedef __attribute__((ext_vector_type(8))) short short8v;
typedef __attribute__((ext_vector_type(4))) float f32x4;
typedef __attribute__((ext_vector_type(4))) unsigned short u16x4;

typedef const __attribute__((address_space(1))) void* gas_ptr;
typedef __attribute__((address_space(3))) void* las_ptr;

static __device__ __forceinline__ unsigned short f2bf(float f) {
  union { float f; unsigned u; } v; v.f = f;
  unsigned u = v.u + 0x7fffu + ((v.u >> 16) & 1u);   // RNE
  return (unsigned short)(u >> 16);
}
static __device__ __forceinline__ float bf2f(unsigned short h) {
  union { unsigned u; float f; } v; v.u = ((unsigned)h) << 16;
  return v.f;
}

// ---------------- K0: sg_w [2000][256] f32 -> wt [256][2048] bf16 (k-minor, zero-padded)
__global__ void k0_transpose_w(const float* __restrict__ sgw, unsigned short* __restrict__ wt) {
  __shared__ __align__(16) unsigned short st[32][40];   // padded
  const int t = threadIdx.x;
  const int d0 = blockIdx.x * 32;     // 64 tiles cover 0..2047
  const int o0 = blockIdx.y * 32;     // 8 tiles
  {
    int dl = t >> 3, oq = (t & 7) * 4;
    int d = d0 + dl;
    f32x4 v = {0.f, 0.f, 0.f, 0.f};
    if (d < D_FEAT) v = *(const f32x4*)&sgw[(size_t)d * N_OUT + o0 + oq];
    st[dl][oq + 0] = f2bf(v[0]); st[dl][oq + 1] = f2bf(v[1]);
    st[dl][oq + 2] = f2bf(v[2]); st[dl][oq + 3] = f2bf(v[3]);
  }
  __syncthreads();
  {
    int ol = t >> 3, dq = (t & 7) * 4;
    int o = o0 + ol;
    u16x4 u;
    u[0] = st[dq + 0][ol]; u[1] = st[dq + 1][ol];
    u[2] = st[dq + 2][ol]; u[3] = st[dq + 3][ol];
    *(u16x4*)&wt[(size_t)o * D_PAD + d0 + dq] = u;
  }
}

// ---------------- K1: nv partial GEMMs (fp32): emb[64,2000]@W[2000,2000]
// grid (16 coltile, 20 ksplit, 2 mat); krange=100 per split, chunks 64+36.
// partials staged in d_out (dead until K3 overwrites): [2][20][64][2048]
__global__ __launch_bounds__(256, 4) void k1_nv_partial(
    const float* __restrict__ emb1, const float* __restrict__ emb2,
    const float* __restrict__ w1, const float* __restrict__ w2,
    float* __restrict__ part) {
  __shared__ __align__(16) float et[64 * 64];    // [i][d] 16KB, XOR-swizzled 16B chunks
  __shared__ __align__(16) float wt_s[64 * 128]; // [d][c] 32KB, XOR-swizzled
  const int t  = threadIdx.x;
  const int ct = blockIdx.x;     // col tile (128 cols)
  const int ks = blockIdx.y;     // ksplit
  const int mat = blockIdx.z;
  const float* emb = mat ? emb2 : emb1;
  const float* w   = mat ? w2 : w1;
  const int kbase = ks * 100;
  const int rg = t >> 5;         // rows rg*8..+7
  const int cg = t & 31;         // cols cg*4..+3

  float acc[8][4];
#pragma unroll
  for (int r = 0; r < 8; ++r)
#pragma unroll
    for (int c = 0; c < 4; ++c) acc[r][c] = 0.f;

  for (int c0 = 0; c0 < 100; c0 += 64) {
    const int bkc = (100 - c0) < 64 ? (100 - c0) : 64;
    if (c0) __syncthreads();
    {  // stage et [i][d]: thread i=t>>2, kq=(t&3)*16
      int i = t >> 2, kq = (t & 3) * 16;
      const float* src = &emb[(size_t)i * D_FEAT + kbase + c0];
#pragma unroll
      for (int u = 0; u < 4; ++u) {
        int kk = kq + u * 4;
        f32x4 v = {0.f, 0.f, 0.f, 0.f};
        if (kk + 3 < bkc) v = *(const f32x4*)&src[kk];
        else {
          if (kk + 0 < bkc) v[0] = src[kk + 0];
          if (kk + 1 < bkc) v[1] = src[kk + 1];
          if (kk + 2 < bkc) v[2] = src[kk + 2];
          if (kk + 3 < bkc) v[3] = src[kk + 3];
        }
        int byte = (i * 256 + kk * 4) ^ ((i & 7) << 4);
        *(f32x4*)((char*)et + byte) = v;
      }
    }
    {  // stage wt_s [d][c]: thread d=t>>2, cb=(t&3)*32
      int d = t >> 2, cb = (t & 3) * 32;
      int gk = kbase + c0 + d;
      const float* srcw = &w[(size_t)gk * D_FEAT + ct * 128 + cb];
#pragma unroll
      for (int u = 0; u < 8; ++u) {
        int c = cb + u * 4;
        int gc = ct * 128 + c;
        f32x4 v = {0.f, 0.f, 0.f, 0.f};
        if (d < bkc && gc + 3 < D_FEAT) v = *(const f32x4*)&srcw[u * 4];
        int byte = (d * 512 + c * 4) ^ ((d & 7) << 4);
        *(f32x4*)((char*)wt_s + byte) = v;
      }
    }
    __syncthreads();
    for (int d4 = 0; d4 < 64; d4 += 4) {
      f32x4 a[8], bq[4];
#pragma unroll
      for (int r = 0; r < 8; ++r) {
        int row = rg * 8 + r;
        int byte = (row * 256 + d4 * 4) ^ ((row & 7) << 4);
        a[r] = *(const f32x4*)((const char*)et + byte);
      }
#pragma unroll
      for (int u = 0; u < 4; ++u) {
        int d = d4 + u;
        int byte = (d * 512 + cg * 16) ^ ((d & 7) << 4);
        bq[u] = *(const f32x4*)((const char*)wt_s + byte);
      }
#pragma unroll
      for (int r = 0; r < 8; ++r)
#pragma unroll
        for (int u = 0; u < 4; ++u) {
          acc[r][0] += a[r][u] * bq[u][0];
          acc[r][1] += a[r][u] * bq[u][1];
          acc[r][2] += a[r][u] * bq[u][2];
          acc[r][3] += a[r][u] * bq[u][3];
        }
    }
  }
  size_t base = (size_t)(mat * 20 + ks) * 64 * 2048;
#pragma unroll
  for (int r = 0; r < 8; ++r) {
    int i = rg * 8 + r;
    int c = ct * 128 + cg * 4;
    f32x4 v = {acc[r][0], acc[r][1], acc[r][2], acc[r][3]};
    *(f32x4*)&part[base + (size_t)i * 2048 + c] = v;
  }
}

// ---------------- K1b: reduce 20 partials + tanh -> nv [2][64][2000]
__global__ void k1b_reduce_tanh(const float* __restrict__ part,
                                const float* __restrict__ b1, const float* __restrict__ b2,
                                float* __restrict__ nv) {
  int id = blockIdx.x * 256 + threadIdx.x;   // 0..63999 over [2][64][500]
  int c4  = (id % 500) * 4;
  int i   = (id / 500) % 64;
  int mat = id / (500 * 64);
  f32x4 s = {0.f, 0.f, 0.f, 0.f};
  for (int ks = 0; ks < 20; ++ks)
    s += *(const f32x4*)&part[(((size_t)(mat * 20 + ks) * 64 + i) * 2048) + c4];
  const float* bias = mat ? b2 : b1;
  f32x4 bv = *(const f32x4*)&bias[c4];
  f32x4 r;
#pragma unroll
  for (int u = 0; u < 4; ++u) r[u] = tanhf(ALPHA * (s[u] + bv[u]));
  *(f32x4*)&nv[((size_t)mat * 64 + i) * D_FEAT + c4] = r;
}

// ---------------- K2a: M[i][j] = dot(nv1[i], nv2[j]) over 2000
__global__ void k2a_scores(const float* __restrict__ nv, float* __restrict__ M) {
  const int i  = blockIdx.x >> 2;
  const int jg = blockIdx.x & 3;
  const int t = threadIdx.x;
  const int wv = t >> 6, lane = t & 63;
  const float* n1 = nv + (size_t)i * D_FEAT;
  for (int q = 0; q < 4; ++q) {
    int j = jg * 16 + wv * 4 + q;
    const float* n2 = nv + (size_t)(64 + j) * D_FEAT;
    float s = 0.f;
    for (int it = 0; it < 32; ++it) {
      int d = it * 64 + lane;
      if (d < D_FEAT) s += n1[d] * n2[d];
    }
    for (int off = 32; off; off >>= 1) s += __shfl_xor(s, off, 64);
    if (lane == 0) M[i * 64 + j] = s;
  }
}

// ---------------- K2b: adj -> top3 mask -> gcn_norm -> A^3 (transposed) ; single block
__global__ __launch_bounds__(1024) void k2b_graph(const float* __restrict__ M,
                                                  float* __restrict__ a3t) {
  __shared__ __align__(16) float m2[64 * 64];   // M, later A2
  __shared__ __align__(16) float ah[64 * 68];   // ahat (padded)
  __shared__ __align__(16) float an[64 * 68];   // anorm (padded)
  __shared__ float dinv[64];
  const int t = threadIdx.x;
  for (int e = t; e < 4096; e += 1024) m2[e] = M[e];
  __syncthreads();
  for (int e = t; e < 4096; e += 1024) {
    int i = e >> 6, j = e & 63;
    float a = m2[i * 64 + j] - m2[j * 64 + i];
    float v = tanhf(ALPHA * a);
    ah[i * 68 + j] = v > 0.f ? v : 0.f;
  }
  __syncthreads();
  if (t < 64) {    // per-row top-3 (ties -> lowest index, matches lax.top_k)
    int i = t;
    int j1 = -1, j2 = -1, j3 = -1;
    float v1 = -1.f, v2 = -1.f, v3 = -1.f;
    for (int j = 0; j < 64; ++j) { float v = ah[i * 68 + j]; if (v > v1) { v1 = v; j1 = j; } }
    for (int j = 0; j < 64; ++j) { if (j == j1) continue; float v = ah[i * 68 + j]; if (v > v2) { v2 = v; j2 = j; } }
    for (int j = 0; j < 64; ++j) { if (j == j1 || j == j2) continue; float v = ah[i * 68 + j]; if (v > v3) { v3 = v; j3 = j; } }
    for (int j = 0; j < 64; ++j) {
      float keep = (j == j1 || j == j2 || j == j3) ? ah[i * 68 + j] : 0.f;
      if (j == i) keep += 1.f;     // self loop
      ah[i * 68 + j] = keep;
    }
  }
  __syncthreads();
  if (t < 64) {     // column (dst) degree
    int j = t; float s = 0.f;
    for (int i = 0; i < 64; ++i) s += ah[i * 68 + j];
    dinv[j] = rsqrtf(s);
  }
  __syncthreads();
  for (int e = t; e < 4096; e += 1024) {   // anorm[i][j] = dinv[i]*ahat[j][i]*dinv[j]
    int i = e >> 6, j = e & 63;
    an[i * 68 + j] = dinv[i] * ah[j * 68 + i] * dinv[j];
  }
  __syncthreads();
  {  // A2 = an @ an -> m2
    int i = t >> 4, j4 = (t & 15) * 4;
    f32x4 s = {0.f, 0.f, 0.f, 0.f};
    for (int k = 0; k < 64; ++k) s += an[i * 68 + k] * *(const f32x4*)&an[k * 68 + j4];
    m2[i * 64 + j4 + 0] = s[0]; m2[i * 64 + j4 + 1] = s[1];
    m2[i * 64 + j4 + 2] = s[2]; m2[i * 64 + j4 + 3] = s[3];
  }
  __syncthreads();
  {  // A3 = A2 @ an, store transposed a3t[j][i]
    int i = t >> 4, j4 = (t & 15) * 4;
    f32x4 s = {0.f, 0.f, 0.f, 0.f};
    for (int k = 0; k < 64; ++k) s += m2[i * 64 + k] * *(const f32x4*)&an[k * 68 + j4];
    a3t[(j4 + 0) * 64 + i] = s[0];
    a3t[(j4 + 1) * 64 + i] = s[1];
    a3t[(j4 + 2) * 64 + i] = s[2];
    a3t[(j4 + 3) * 64 + i] = s[3];
  }
}

// ---------------- K3: per-batch fused y=x@W (bf16 MFMA) then out = relu(A3@y + b)
__global__ __launch_bounds__(512, 4) void k3_fused(
    const float* __restrict__ x, const unsigned short* __restrict__ wt,
    const float* __restrict__ a3t, const float* __restrict__ sgb,
    float* __restrict__ out) {
  __shared__ __align__(16) char smem[49152];  // [0,8K) x_lds ; [8K,40K) w_lds ; epi: y[0,32K), a3[32K,48K)
  const int t = threadIdx.x;
  const int b = blockIdx.x;
  const int wv = t >> 6;
  const int lane = t & 63;
  const int l15 = lane & 15;
  const int lg = lane >> 4;
  const int wr = wv >> 2;     // 0..1 : 32-node half
  const int wc = wv & 3;      // 0..3 : 64-out quarter
  const float* xb = x + (size_t)b * (64 * D_FEAT);

  f32x4 acc[2][4];
#pragma unroll
  for (int m = 0; m < 2; ++m)
#pragma unroll
    for (int n = 0; n < 4; ++n) acc[m][n] = (f32x4){0.f, 0.f, 0.f, 0.f};

  const int sx_node = t >> 3;
  const int sx_ko = (t & 7) * 8;
  const int sx_byte = (sx_node * 128 + sx_ko * 2) ^ ((sx_node & 7) << 4);
  const float* xrow = xb + (size_t)sx_node * D_FEAT + sx_ko;

  // global_load_lds: linear LDS dest, inverse-swizzled global source (m173 pattern)
  int wsrc_off[4];
#pragma unroll
  for (int c = 0; c < 4; ++c) {
    int p = wv * 4096 + c * 1024 + lane * 16;          // phys LDS byte (rel. to w base)
    int o = p >> 7;                                    // out row (128B rows)
    int kb = (p & 127) ^ ((o & 7) << 4);               // logical k-byte
    wsrc_off[c] = o * (D_PAD * 2) + kb;
  }

  for (int step = 0; step < 32; ++step) {
    const int k0 = step * 64;
    const int rem = D_FEAT - k0;   // 64 except last step (16)
    {  // x stage: f32 -> bf16, XOR-swizzled ds_write_b128
      f32x4 v0 = {0.f, 0.f, 0.f, 0.f}, v1 = {0.f, 0.f, 0.f, 0.f};
      if (sx_ko < rem) {
        v0 = *(const f32x4*)&xrow[k0];
        v1 = *(const f32x4*)&xrow[k0 + 4];
      }
      short8v s;
      s[0] = (short)f2bf(v0[0]); s[1] = (short)f2bf(v0[1]);
      s[2] = (short)f2bf(v0[2]); s[3] = (short)f2bf(v0[3]);
      s[4] = (short)f2bf(v1[0]); s[5] = (short)f2bf(v1[1]);
      s[6] = (short)f2bf(v1[2]); s[7] = (short)f2bf(v1[3]);
      *(short8v*)(smem + sx_byte) = s;
    }
#pragma unroll
    for (int c = 0; c < 4; ++c) {   // w stage: async 16B direct-to-LDS
      const char* src = (const char*)wt + wsrc_off[c] + k0 * 2;
      char* dst = smem + 8192 + wv * 4096 + c * 1024;  // wave-uniform base
      __builtin_amdgcn_global_load_lds((gas_ptr)src, (las_ptr)dst, 16, 0, 0);
    }
    __syncthreads();
#pragma unroll
    for (int kk = 0; kk < 2; ++kk) {
      short8v af[2], bf[4];
#pragma unroll
      for (int m = 0; m < 2; ++m) {
        int row = wr * 32 + m * 16 + l15;
        int byte = (row * 128 + kk * 64 + lg * 16) ^ ((row & 7) << 4);
        af[m] = *(const short8v*)(smem + byte);
      }
#pragma unroll
      for (int n = 0; n < 4; ++n) {
        int o = wc * 64 + n * 16 + l15;
        int byte = 8192 + ((o * 128 + kk * 64 + lg * 16) ^ ((o & 7) << 4));
        bf[n] = *(const short8v*)(smem + byte);
      }
#pragma unroll
      for (int m = 0; m < 2; ++m)
#pragma unroll
        for (int n = 0; n < 4; ++n)
          acc[m][n] = __builtin_amdgcn_mfma_f32_16x16x32_bf16(af[m], bf[n], acc[m][n], 0, 0, 0);
    }
    __syncthreads();
  }

  // epilogue: y -> LDS (bf16), node-mix with A3, bias, relu
  unsigned short* yl = (unsigned short*)smem;       // [64][256] bf16
#pragma unroll
  for (int m = 0; m < 2; ++m)
#pragma unroll
    for (int n = 0; n < 4; ++n) {
      int row0 = wr * 32 + m * 16 + lg * 4;
      int col = wc * 64 + n * 16 + l15;
#pragma unroll
      for (int r = 0; r < 4; ++r)
        yl[(row0 + r) * 256 + col] = f2bf(acc[m][n][r]);
    }
  float* a3l = (float*)(smem + 32768);              // a3t[j][i]
  for (int e = t; e < 4096; e += 512) a3l[e] = a3t[e];
  __syncthreads();
  {
    const int o4 = (t & 63) * 4;
    const int ig = t >> 6;       // nodes ig*8..+7
    f32x4 bv = *(const f32x4*)&sgb[o4];
    f32x4 res[8];
#pragma unroll
    for (int r = 0; r < 8; ++r) res[r] = bv;
    for (int j = 0; j < 64; ++j) {
      f32x4 a0 = *(const f32x4*)&a3l[j * 64 + ig * 8];
      f32x4 a1 = *(const f32x4*)&a3l[j * 64 + ig * 8 + 4];
      u16x4 yq = *(const u16x4*)&yl[j * 256 + o4];
      f32x4 yv = {bf2f(yq[0]), bf2f(yq[1]), bf2f(yq[2]), bf2f(yq[3])};
      res[0] += a0[0] * yv; res[1] += a0[1] * yv;
      res[2] += a0[2] * yv; res[3] += a0[3] * yv;
      res[4] += a1[0] * yv; res[5] += a1[1] * yv;
      res[6] += a1[2] * yv; res[7] += a1[3] * yv;
    }
#pragma unroll
    for (int r = 0; r < 8; ++r) {
      f32x4 v = res[r];
#pragma unroll
      for (int u = 0; u < 4; ++u) v[u] = fmaxf(v[u], 0.f);
      *(f32x4*)&out[(size_t)b * 16384 + (size_t)(ig * 8 + r) * 256 + o4] = v;
    }
  }
}

extern "C" void kernel_launch(void* const* d_in, const int* in_sizes, int n_in,
                              void* d_out, int out_size, void* d_ws, size_t ws_size,
                              hipStream_t stream) {
  const float* x    = (const float*)d_in[0];
  const float* emb1 = (const float*)d_in[1];
  const float* emb2 = (const float*)d_in[2];
  const float* w1   = (const float*)d_in[3];
  const float* b1   = (const float*)d_in[4];
  const float* w2   = (const float*)d_in[5];
  const float* b2   = (const float*)d_in[6];
  const float* sgw  = (const float*)d_in[7];
  const float* sgb  = (const float*)d_in[8];
  float* out = (float*)d_out;

  char* ws = (char*)d_ws;
  float* nv  = (float*)ws;                                      // [2][64][2000] = 1,024,000 B
  float* Mm  = (float*)(ws + 1024000);                          // [64][64]
  float* a3t = (float*)(ws + 1024000 + 16384);                  // [64][64] transposed A^3
  unsigned short* wt = (unsigned short*)(ws + 1024000 + 32768); // [256][2048] bf16 = 1 MB
  float* part = out;  // d_out as scratch: [2][20][64][2048] f32 = 21 MB < 33.5 MB; K3 overwrites all of d_out

  k0_transpose_w<<<dim3(64, 8), 256, 0, stream>>>(sgw, wt);
  k1_nv_partial<<<dim3(16, 20, 2), 256, 0, stream>>>(emb1, emb2, w1, w2, part);
  k1b_reduce_tanh<<<dim3(250), 256, 0, stream>>>(part, b1, b2, nv);
  k2a_scores<<<dim3(256), 256, 0, stream>>>(nv, Mm);
  k2b_graph<<<dim3(1), 1024, 0, stream>>>(Mm, a3t);
  k3_fused<<<dim3(512), 512, 0, stream>>>(x, wt, a3t, sgb, out);
}